// Round 2
// baseline (181.133 us; speedup 1.0000x reference)
//
#include <hip/hip_runtime.h>
#include <stdint.h>

// CoEncoderDynamicAttention: B=2,S=2048,H=1024,NH=16,NKV=4,HD=64, out=(B,S,1)
// Key algebraic rewrite: out[b,q] = sum_h (sum_k e_{hqk} * vproj[b,h,k]) / (sum_k e_{hqk})
// with vproj = hs @ (wv-folded-with-wo) -> the attn@V GEMM disappears.
// exp2 trick: Q' = hs@wq * (log2e/8), so score' = Q'.K and softmax weight = exp2(score').
// Mask folded multiplicatively into num & den (exact equivalent of -inf masking).

#define KS_ 8            // k-splits in attention (partials are linear: no max-subtraction)
#define KRANGE 256       // 2048/KS_
#define TK_ 128          // staged K rows per LDS tile

typedef __bf16 bf16x8 __attribute__((ext_vector_type(8)));
typedef float f32x4 __attribute__((ext_vector_type(4)));

__device__ inline unsigned short f2bf(float f) {
    unsigned int u = __builtin_bit_cast(unsigned int, f);
    u += 0x7fff + ((u >> 16) & 1);   // RNE
    return (unsigned short)(u >> 16);
}
__device__ inline bf16x8 ldfrag(const unsigned short* p) {
    uint4 v = *(const uint4*)p;
    return __builtin_bit_cast(bf16x8, v);
}

#define SCALE_Q 0.18033688011112042f   // log2(e)/8

// ---------------- prep: hs->bf16; wT = [wq^T*s | wk^T | wvo^T | zeros] (1408x1024 bf16)
__global__ __launch_bounds__(256) void prep_kernel(
    const float* __restrict__ hs, const float* __restrict__ wq,
    const float* __restrict__ wk, const float* __restrict__ wv,
    const float* __restrict__ wo,
    unsigned short* __restrict__ hs_bf, unsigned short* __restrict__ wT)
{
    int bid = blockIdx.x, tid = threadIdx.x;
    if (bid < 4096) {
        // hs convert: 4,194,304 f32 -> bf16, 4/thread
        int u = bid * 256 + tid;
        float4 v = ((const float4*)hs)[u];
        ushort4 o;
        o.x = f2bf(v.x); o.y = f2bf(v.y); o.z = f2bf(v.z); o.w = f2bf(v.w);
        ((ushort4*)hs_bf)[u] = o;
    } else if (bid < 4416) {
        // transpose+convert wq (scaled) / wk into wT rows [0,1280)
        __shared__ float tile[64 * 65];
        int t = bid - 4096;
        int ntile = t / 16, ctile = t % 16;
        int nb = ntile * 64, cb = ctile * 64;
        int tx = tid & 63, ty = tid >> 6;
        for (int i = 0; i < 16; i++) {
            int cl = i * 4 + ty;
            int n = nb + tx;
            float v = (n < 1024) ? wq[(cb + cl) * 1024 + n] * SCALE_Q
                                 : wk[(cb + cl) * 256 + (n - 1024)];
            tile[cl * 65 + tx] = v;
        }
        __syncthreads();
        for (int i = 0; i < 16; i++) {
            int nl = i * 4 + ty;
            wT[(nb + nl) * 1024 + cb + tx] = f2bf(tile[tx * 65 + nl]);
        }
    } else {
        // rows [1280,1296): wvo^T[h][c] = sum_d wv[c][(h>>2)*64+d]*wo[h*64+d]; rows [1296,1408): 0
        int u = (bid - 4416) * 256 + tid;   // 131072 units
        int n2 = u >> 10, c = u & 1023;
        if (n2 < 16) {
            int h = n2, kv = h >> 2;
            const float* wvr = wv + c * 256 + kv * 64;
            const float* wor = wo + h * 64;
            float s = 0.f;
            #pragma unroll 8
            for (int d = 0; d < 64; d++) s += wvr[d] * wor[d];
            wT[(1280 + n2) * 1024 + c] = f2bf(s);
        } else {
            wT[(1280 + n2) * 1024 + c] = 0;
        }
    }
}

// ---------------- gemm: D[n][r] = sum_c wT[n][c]*hs_bf[r][c]  (C^T orientation ->
// lane's 4 acc regs are 4 consecutive n = coalescible 8B bf16 stores)
// n-tiles: 0..7 -> Q' (B,S,1024 bf16), 8..9 -> K (B,S,256 bf16), 10 -> vproj (B,NH,S f32)
__global__ __launch_bounds__(256) void gemm_kernel(
    const unsigned short* __restrict__ hs_bf, const unsigned short* __restrict__ wT,
    unsigned short* __restrict__ Qp, unsigned short* __restrict__ Kp,
    float* __restrict__ vproj)
{
    __shared__ __align__(16) unsigned short Al[128 * 40];  // stride 40: 2-way-max banks
    __shared__ __align__(16) unsigned short Bl[128 * 40];
    int nt = blockIdx.x, rt = blockIdx.y;
    int tid = threadIdx.x;
    int lane = tid & 63, w = tid >> 6;
    int l15 = lane & 15, quad = lane >> 4;
    int wm = (w >> 1) * 64, wn = (w & 1) * 64;

    f32x4 acc[4][4];
    const f32x4 zero = {0.f, 0.f, 0.f, 0.f};
    for (int i = 0; i < 4; i++) for (int j = 0; j < 4; j++) acc[i][j] = zero;

    int arow = nt * 128, rrow = rt * 128;
    for (int kk = 0; kk < 32; kk++) {
        int c0 = kk * 32;
        for (int ph = 0; ph < 2; ph++) {
            int u = ph * 256 + tid;      // 512 x 16B per tile
            int row = u >> 2, ch = u & 3;
            uint4 a = *(const uint4*)(wT + (arow + row) * 1024 + c0 + ch * 8);
            uint4 b = *(const uint4*)(hs_bf + (rrow + row) * 1024 + c0 + ch * 8);
            *(uint4*)(Al + row * 40 + ch * 8) = a;
            *(uint4*)(Bl + row * 40 + ch * 8) = b;
        }
        __syncthreads();
        bf16x8 af[4], bfr[4];
        for (int i = 0; i < 4; i++) {
            af[i]  = ldfrag(Al + (wm + i * 16 + l15) * 40 + quad * 8);
            bfr[i] = ldfrag(Bl + (wn + i * 16 + l15) * 40 + quad * 8);
        }
        for (int i = 0; i < 4; i++)
            for (int j = 0; j < 4; j++)
                acc[i][j] = __builtin_amdgcn_mfma_f32_16x16x32_bf16(af[i], bfr[j], acc[i][j], 0, 0, 0);
        __syncthreads();
    }

    // epilogue: D row (m) = weight col n_w = nt*128+wm+i*16+quad*4+reg ; D col = r = rt*128+wn+j*16+l15
    for (int i = 0; i < 4; i++) {
        for (int j = 0; j < 4; j++) {
            int nw = nt * 128 + wm + i * 16 + quad * 4;
            int r  = rt * 128 + wn + j * 16 + l15;
            if (nt < 8) {
                ushort4 o;
                o.x = f2bf(acc[i][j][0]); o.y = f2bf(acc[i][j][1]);
                o.z = f2bf(acc[i][j][2]); o.w = f2bf(acc[i][j][3]);
                *(ushort4*)(Qp + (size_t)r * 1024 + nw) = o;
            } else if (nt < 10) {
                ushort4 o;
                o.x = f2bf(acc[i][j][0]); o.y = f2bf(acc[i][j][1]);
                o.z = f2bf(acc[i][j][2]); o.w = f2bf(acc[i][j][3]);
                *(ushort4*)(Kp + (size_t)r * 256 + (nw - 1024)) = o;
            } else {
                for (int rg = 0; rg < 4; rg++) {
                    int h = nw + rg - 1280;
                    if (h < 16)
                        vproj[((size_t)(r >> 11) * 16 + h) * 2048 + (r & 2047)] = acc[i][j][rg];
                }
            }
        }
    }
}

// ---------------- attention: per (b,h,qtile128,ksplit): S^T = K·Q'^T via MFMA,
// lane-local num/den accumulation (k-rows live in this lane's regs), quad-reduce at end.
__global__ __launch_bounds__(256) void attn_kernel(
    const unsigned short* __restrict__ Qp, const unsigned short* __restrict__ Kp,
    const float* __restrict__ vproj, const int* __restrict__ mask,
    float2* __restrict__ part)
{
    __shared__ __align__(16) unsigned short Kl[TK_ * 80];  // pad 64->80
    __shared__ __align__(16) float vpml[TK_];
    __shared__ __align__(16) float ml[TK_];
    int qt = blockIdx.x, bh = blockIdx.y, ks = blockIdx.z;
    int b = bh >> 4, h = bh & 15, kv = h >> 2;
    int tid = threadIdx.x, lane = tid & 63, w = tid >> 6;
    int l15 = lane & 15, quad = lane >> 4;

    // Q fragments (held in regs for whole k loop): B-operand layout B[d][q], q=lane&15
    bf16x8 qf[2][2];
    int qrow0 = qt * 128 + w * 32;
    for (int qs = 0; qs < 2; qs++) {
        const unsigned short* qp =
            Qp + (size_t)(b * 2048 + qrow0 + qs * 16 + l15) * 1024 + h * 64 + quad * 8;
        qf[qs][0] = ldfrag(qp);
        qf[qs][1] = ldfrag(qp + 32);
    }
    float num[2] = {0.f, 0.f}, den[2] = {0.f, 0.f};

    for (int t = 0; t < KRANGE / TK_; t++) {
        int k0 = ks * KRANGE + t * TK_;
        for (int i = 0; i < 4; i++) {
            int u = i * 256 + tid;
            int row = u >> 3, ch = u & 7;
            uint4 kd = *(const uint4*)(Kp + (size_t)(b * 2048 + k0 + row) * 256 + kv * 64 + ch * 8);
            *(uint4*)(Kl + row * 80 + ch * 8) = kd;
        }
        if (tid < TK_) {
            float mf = (float)mask[b * 2048 + k0 + tid];
            float vp = vproj[((size_t)b * 16 + h) * 2048 + k0 + tid];
            vpml[tid] = vp * mf;
            ml[tid] = mf;
        }
        __syncthreads();
        for (int t8 = 0; t8 < 8; t8++) {
            const unsigned short* kb = Kl + (t8 * 16 + l15) * 80 + quad * 8;
            bf16x8 a0 = ldfrag(kb);
            bf16x8 a1 = ldfrag(kb + 32);
            f32x4 vpm4 = *(const f32x4*)(vpml + t8 * 16 + quad * 4);
            f32x4 m4   = *(const f32x4*)(ml + t8 * 16 + quad * 4);
            for (int qs = 0; qs < 2; qs++) {
                const f32x4 z = {0.f, 0.f, 0.f, 0.f};
                f32x4 d = __builtin_amdgcn_mfma_f32_16x16x32_bf16(a0, qf[qs][0], z, 0, 0, 0);
                d = __builtin_amdgcn_mfma_f32_16x16x32_bf16(a1, qf[qs][1], d, 0, 0, 0);
                for (int r = 0; r < 4; r++) {
                    float e = __builtin_amdgcn_exp2f(d[r]);   // softmax weight (unnormalized)
                    num[qs] += e * vpm4[r];
                    den[qs] += e * m4[r];
                }
            }
        }
        __syncthreads();
    }
    for (int qs = 0; qs < 2; qs++) {
        float n = num[qs], dd = den[qs];
        n += __shfl_xor(n, 16);  n += __shfl_xor(n, 32);
        dd += __shfl_xor(dd, 16); dd += __shfl_xor(dd, 32);
        if (quad == 0) {
            int q = qrow0 + qs * 16 + l15;
            part[((size_t)(b * 2048 + q) * 16 + h) * 8 + ks] = make_float2(n, dd);
        }
    }
}

// ---------------- combine: out[b,q] = sum_h (sum_ks num)/(sum_ks den); one wave per (b,q)
__global__ __launch_bounds__(256) void combine_kernel(
    const float2* __restrict__ part, float* __restrict__ out)
{
    int wid = (blockIdx.x * 256 + threadIdx.x) >> 6;  // 0..4095 = (b,q)
    int lane = threadIdx.x & 63;
    const float2* base = part + (size_t)wid * 128;    // 16 h x 8 ks
    float2 p0 = base[lane];         // h = lane>>3,      ks = lane&7
    float2 p1 = base[64 + lane];    // h = 8 + (lane>>3)
    for (int m = 1; m <= 4; m <<= 1) {
        p0.x += __shfl_xor(p0.x, m); p0.y += __shfl_xor(p0.y, m);
        p1.x += __shfl_xor(p1.x, m); p1.y += __shfl_xor(p1.y, m);
    }
    float v = p0.x / p0.y + p1.x / p1.y;
    // per-lane v is v_g (g = lane>>3), identical across the 8 lanes of a group.
    // xor-8/16/32 butterfly sums the 8 DISTINCT groups exactly once each -> sum over all 16 h.
    for (int m = 8; m <= 32; m <<= 1) v += __shfl_xor(v, m);
    if (lane == 0) out[wid] = v;
}

extern "C" void kernel_launch(void* const* d_in, const int* in_sizes, int n_in,
                              void* d_out, int out_size, void* d_ws, size_t ws_size,
                              hipStream_t stream)
{
    const float* hs  = (const float*)d_in[0];
    const int* mask  = (const int*)d_in[1];
    const float* wq  = (const float*)d_in[2];
    const float* wk  = (const float*)d_in[3];
    const float* wv  = (const float*)d_in[4];
    const float* wo  = (const float*)d_in[5];

    char* ws = (char*)d_ws;
    unsigned short* hs_bf = (unsigned short*)ws;               // 8,388,608 B
    unsigned short* wT    = (unsigned short*)(ws + 8388608);   // 2,883,584 B (1408x1024 bf16)
    unsigned short* Qp    = (unsigned short*)(ws + 11272192);  // 8,388,608 B
    unsigned short* Kp    = (unsigned short*)(ws + 19660800);  // 2,097,152 B
    float* vproj          = (float*)(ws + 21757952);           //   262,144 B
    float2* part          = (float2*)(ws + 22020096);          // 4,194,304 B  (total ~26.2 MB)

    prep_kernel<<<4928, 256, 0, stream>>>(hs, wq, wk, wv, wo, hs_bf, wT);
    gemm_kernel<<<dim3(11, 32), 256, 0, stream>>>(hs_bf, wT, Qp, Kp, vproj);
    attn_kernel<<<dim3(16, 32, 8), 256, 0, stream>>>(Qp, Kp, vproj, mask, part);
    combine_kernel<<<1024, 256, 0, stream>>>(part, (float*)d_out);
}

// Round 4
// 148.429 us; speedup vs baseline: 1.2203x; 1.2203x over previous
//
#include <hip/hip_runtime.h>
#include <stdint.h>

// CoEncoderDynamicAttention: B=2,S=2048,H=1024,NH=16,NKV=4,HD=64, out=(B,S,1)
// out[b,q] = sum_h (sum_k e_{hqk} * vproj[b,h,k]) / (sum_k e_{hqk})
// vproj = hs @ (wv folded with wo)  -> attn@V GEMM eliminated.
// Q' = hs@wq * (log2e/8)  -> weight = exp2(Q'.K).
// Mask folded as accumulator-init bias (0 / -30000) -> exp2 gives exact 0.

typedef __bf16 bf16x8 __attribute__((ext_vector_type(8)));
typedef float f32x4 __attribute__((ext_vector_type(4)));

__device__ inline unsigned short f2bf(float f) {
    unsigned int u = __builtin_bit_cast(unsigned int, f);
    u += 0x7fff + ((u >> 16) & 1);   // RNE
    return (unsigned short)(u >> 16);
}
__device__ inline bf16x8 ldfrag(const unsigned short* p) {
    uint4 v = *(const uint4*)p;
    return __builtin_bit_cast(bf16x8, v);
}
__device__ inline void gl2lds16(const unsigned short* g, unsigned short* l) {
    // 64 lanes x 16B: per-lane global addr, LDS dst = wave-uniform base + lane*16
    __builtin_amdgcn_global_load_lds(
        (const __attribute__((address_space(1))) void*)g,
        (__attribute__((address_space(3))) void*)l, 16, 0, 0);
}

#define SCALE_Q 0.18033688011112042f   // log2(e)/8

// ---------------- prep: hs->bf16; wT = [wq^T*s | wk^T | wvo^T | zeros] (1408x1024 bf16)
__global__ __launch_bounds__(256) void prep_kernel(
    const float* __restrict__ hs, const float* __restrict__ wq,
    const float* __restrict__ wk, const float* __restrict__ wv,
    const float* __restrict__ wo,
    unsigned short* __restrict__ hs_bf, unsigned short* __restrict__ wT)
{
    int bid = blockIdx.x, tid = threadIdx.x;
    if (bid < 4096) {
        int u = bid * 256 + tid;
        float4 v = ((const float4*)hs)[u];
        ushort4 o;
        o.x = f2bf(v.x); o.y = f2bf(v.y); o.z = f2bf(v.z); o.w = f2bf(v.w);
        ((ushort4*)hs_bf)[u] = o;
    } else if (bid < 4416) {
        __shared__ float tile[64 * 65];
        int t = bid - 4096;
        int ntile = t / 16, ctile = t % 16;
        int nb = ntile * 64, cb = ctile * 64;
        int tx = tid & 63, ty = tid >> 6;
        for (int i = 0; i < 16; i++) {
            int cl = i * 4 + ty;
            int n = nb + tx;
            float v = (n < 1024) ? wq[(cb + cl) * 1024 + n] * SCALE_Q
                                 : wk[(cb + cl) * 256 + (n - 1024)];
            tile[cl * 65 + tx] = v;
        }
        __syncthreads();
        for (int i = 0; i < 16; i++) {
            int nl = i * 4 + ty;
            wT[(nb + nl) * 1024 + cb + tx] = f2bf(tile[tx * 65 + nl]);
        }
    } else {
        int u = (bid - 4416) * 256 + tid;
        int n2 = u >> 10, c = u & 1023;
        if (n2 < 16) {
            int h = n2, kv = h >> 2;
            const float* wvr = wv + c * 256 + kv * 64;
            const float* wor = wo + h * 64;
            float s = 0.f;
            #pragma unroll 8
            for (int d = 0; d < 64; d++) s += wvr[d] * wor[d];
            wT[(1280 + n2) * 1024 + c] = f2bf(s);
        } else {
            wT[(1280 + n2) * 1024 + c] = 0;
        }
    }
}

// ---------------- gemm (m97 structure): D[n][r] = sum_c wT[n][c]*hs_bf[r][c]
// n-tiles: 0..7 -> Q' bf16, 8..9 -> K bf16, 10 -> vproj f32
__global__ __launch_bounds__(256) void gemm_kernel(
    const unsigned short* __restrict__ hs_bf, const unsigned short* __restrict__ wT,
    unsigned short* __restrict__ Qp, unsigned short* __restrict__ Kp,
    float* __restrict__ vproj)
{
    __shared__ __align__(16) unsigned short Al[128 * 32];  // unpadded: global_load_lds lane order
    __shared__ __align__(16) unsigned short Bl[128 * 32];
    int nt = blockIdx.x, rt = blockIdx.y;
    int tid = threadIdx.x;
    int lane = tid & 63, w = tid >> 6;
    int l15 = lane & 15, quad = lane >> 4;
    int wm = (w >> 1) * 64, wn = (w & 1) * 64;

    f32x4 acc[4][4];
    const f32x4 zero = {0.f, 0.f, 0.f, 0.f};
    for (int i = 0; i < 4; i++) for (int j = 0; j < 4; j++) acc[i][j] = zero;

    int arow = nt * 128, rrow = rt * 128;
    // staging: wave w covers rows w*32..w*32+31 in two 16-row chunks
    int srow = w * 32 + (lane >> 2);
    int scol = (lane & 3) * 8;
    const unsigned short* ga = wT    + (size_t)(arow + srow) * 1024 + scol;
    const unsigned short* gb = hs_bf + (size_t)(rrow + srow) * 1024 + scol;
    unsigned short* la = Al + (w * 32) * 32;
    unsigned short* lb = Bl + (w * 32) * 32;

    for (int kk = 0; kk < 32; kk++) {
        gl2lds16(ga,             la);
        gl2lds16(ga + 16 * 1024, la + 16 * 32);
        gl2lds16(gb,             lb);
        gl2lds16(gb + 16 * 1024, lb + 16 * 32);
        ga += 32; gb += 32;
        __syncthreads();
        bf16x8 af[4], bfr[4];
        for (int i = 0; i < 4; i++) {
            af[i]  = ldfrag(Al + (wm + i * 16 + l15) * 32 + quad * 8);
            bfr[i] = ldfrag(Bl + (wn + i * 16 + l15) * 32 + quad * 8);
        }
        for (int i = 0; i < 4; i++)
            for (int j = 0; j < 4; j++)
                acc[i][j] = __builtin_amdgcn_mfma_f32_16x16x32_bf16(af[i], bfr[j], acc[i][j], 0, 0, 0);
        __syncthreads();
    }

    for (int i = 0; i < 4; i++) {
        for (int j = 0; j < 4; j++) {
            int nw = nt * 128 + wm + i * 16 + quad * 4;
            int r  = rt * 128 + wn + j * 16 + l15;
            if (nt < 8) {
                ushort4 o;
                o.x = f2bf(acc[i][j][0]); o.y = f2bf(acc[i][j][1]);
                o.z = f2bf(acc[i][j][2]); o.w = f2bf(acc[i][j][3]);
                *(ushort4*)(Qp + (size_t)r * 1024 + nw) = o;
            } else if (nt < 10) {
                ushort4 o;
                o.x = f2bf(acc[i][j][0]); o.y = f2bf(acc[i][j][1]);
                o.z = f2bf(acc[i][j][2]); o.w = f2bf(acc[i][j][3]);
                *(ushort4*)(Kp + (size_t)r * 256 + (nw - 1024)) = o;
            } else {
                for (int rg = 0; rg < 4; rg++) {
                    int h = nw + rg - 1280;
                    if (h < 16)
                        vproj[((size_t)(r >> 11) * 16 + h) * 2048 + (r & 2047)] = acc[i][j][rg];
                }
            }
        }
    }
}

// ---------------- attention v2: block = (b,kv,qtile64,ks256); wave w -> h = kv*4+w.
// One shared K tile (256x64) staged once; 4 independent q-chains per wave;
// mask enters as MFMA accumulator-init bias.
__global__ __launch_bounds__(256) void attn_kernel(
    const unsigned short* __restrict__ Qp, const unsigned short* __restrict__ Kp,
    const float* __restrict__ vproj, const int* __restrict__ mask,
    float2* __restrict__ part)
{
    __shared__ __align__(16) unsigned short Kl[256 * 80];  // stride 80: measured 0 conflicts
    __shared__ __align__(16) float vpml[4 * 256];
    __shared__ __align__(16) float biasl[256];
    int qt = blockIdx.x;                       // 0..31
    int b = blockIdx.y >> 2, kv = blockIdx.y & 3;
    int ks = blockIdx.z;                       // 0..7
    int tid = threadIdx.x, lane = tid & 63, w = tid >> 6;
    int l15 = lane & 15, quad = lane >> 4;
    int h = kv * 4 + w;
    int k0 = ks * 256;
    int qrow0 = qt * 64;

    // Q fragments: B-operand layout B[n=q (l15)][k=d (quad*8..)]
    bf16x8 qf[4][2];
    for (int qs = 0; qs < 4; qs++) {
        const unsigned short* qp =
            Qp + (size_t)(b * 2048 + qrow0 + qs * 16 + l15) * 1024 + h * 64 + quad * 8;
        qf[qs][0] = ldfrag(qp);
        qf[qs][1] = ldfrag(qp + 32);
    }

    // stage K (256 rows x 64 d): 256 rows x 8 chunks of 8 shorts = 2048 units
    for (int it = 0; it < 8; it++) {
        int u = it * 256 + tid;
        int row = u >> 3, ch = u & 7;
        *(uint4*)(Kl + row * 80 + ch * 8) =
            *(const uint4*)(Kp + (size_t)(b * 2048 + k0 + row) * 256 + kv * 64 + ch * 8);
    }
    {   // vproj slice per h (4 h x 256 k)
        int h2 = tid >> 6, kk = (tid & 63) * 4;
        *(float4*)(vpml + h2 * 256 + kk) =
            *(const float4*)(vproj + ((size_t)b * 16 + kv * 4 + h2) * 2048 + k0 + kk);
    }
    if (tid < 64) {
        int4 mm = *(const int4*)(mask + b * 2048 + k0 + tid * 4);
        float4 bb;
        bb.x = mm.x ? 0.f : -30000.f;
        bb.y = mm.y ? 0.f : -30000.f;
        bb.z = mm.z ? 0.f : -30000.f;
        bb.w = mm.w ? 0.f : -30000.f;
        *(float4*)(biasl + tid * 4) = bb;
    }
    __syncthreads();

    float num[4] = {0.f, 0.f, 0.f, 0.f}, den[4] = {0.f, 0.f, 0.f, 0.f};
    for (int t8 = 0; t8 < 16; t8++) {
        const unsigned short* kb = Kl + (t8 * 16 + l15) * 80 + quad * 8;
        bf16x8 a0 = ldfrag(kb);           // A[m=k-row (l15)][k=d 0..31]
        bf16x8 a1 = ldfrag(kb + 32);      // d 32..63
        f32x4 vpm4 = *(const f32x4*)(vpml + w * 256 + t8 * 16 + quad * 4);
        f32x4 c4   = *(const f32x4*)(biasl + t8 * 16 + quad * 4);  // mask bias per k-row
        for (int qs = 0; qs < 4; qs++) {
            f32x4 d = __builtin_amdgcn_mfma_f32_16x16x32_bf16(a0, qf[qs][0], c4, 0, 0, 0);
            d = __builtin_amdgcn_mfma_f32_16x16x32_bf16(a1, qf[qs][1], d, 0, 0, 0);
            for (int r = 0; r < 4; r++) {
                float e = __builtin_amdgcn_exp2f(d[r]);   // 0 for masked rows
                num[qs] += e * vpm4[r];
                den[qs] += e;
            }
        }
    }
    for (int qs = 0; qs < 4; qs++) {
        float n = num[qs], dd = den[qs];
        n += __shfl_xor(n, 16);  n += __shfl_xor(n, 32);
        dd += __shfl_xor(dd, 16); dd += __shfl_xor(dd, 32);
        if (quad == 0) {
            int q = qrow0 + qs * 16 + l15;
            part[((size_t)(b * 2048 + q) * 16 + h) * 8 + ks] = make_float2(n, dd);
        }
    }
}

// ---------------- combine: out[b,q] = sum_h (sum_ks num)/(sum_ks den)
__global__ __launch_bounds__(256) void combine_kernel(
    const float2* __restrict__ part, float* __restrict__ out)
{
    int wid = (blockIdx.x * 256 + threadIdx.x) >> 6;  // (b,q)
    int lane = threadIdx.x & 63;
    const float2* base = part + (size_t)wid * 128;    // 16 h x 8 ks
    float2 p0 = base[lane];
    float2 p1 = base[64 + lane];
    for (int m = 1; m <= 4; m <<= 1) {
        p0.x += __shfl_xor(p0.x, m); p0.y += __shfl_xor(p0.y, m);
        p1.x += __shfl_xor(p1.x, m); p1.y += __shfl_xor(p1.y, m);
    }
    float v = p0.x / p0.y + p1.x / p1.y;
    for (int m = 8; m <= 32; m <<= 1) v += __shfl_xor(v, m);  // 8 distinct h-groups, once each
    if (lane == 0) out[wid] = v;
}

extern "C" void kernel_launch(void* const* d_in, const int* in_sizes, int n_in,
                              void* d_out, int out_size, void* d_ws, size_t ws_size,
                              hipStream_t stream)
{
    const float* hs  = (const float*)d_in[0];
    const int* mask  = (const int*)d_in[1];
    const float* wq  = (const float*)d_in[2];
    const float* wk  = (const float*)d_in[3];
    const float* wv  = (const float*)d_in[4];
    const float* wo  = (const float*)d_in[5];

    char* ws = (char*)d_ws;
    unsigned short* hs_bf = (unsigned short*)ws;               // 8,388,608 B
    unsigned short* wT    = (unsigned short*)(ws + 8388608);   // 2,883,584 B
    unsigned short* Qp    = (unsigned short*)(ws + 11272192);  // 8,388,608 B
    unsigned short* Kp    = (unsigned short*)(ws + 19660800);  // 2,097,152 B
    float* vproj          = (float*)(ws + 21757952);           //   262,144 B
    float2* part          = (float2*)(ws + 22020096);          // 4,194,304 B

    prep_kernel<<<4928, 256, 0, stream>>>(hs, wq, wk, wv, wo, hs_bf, wT);
    gemm_kernel<<<dim3(11, 32), 256, 0, stream>>>(hs_bf, wT, Qp, Kp, vproj);
    attn_kernel<<<dim3(32, 8, 8), 256, 0, stream>>>(Qp, Kp, vproj, mask, part);
    combine_kernel<<<1024, 256, 0, stream>>>(part, (float*)d_out);
}